// Round 1
// baseline (822.852 us; speedup 1.0000x reference)
//
#include <hip/hip_runtime.h>
#include <math.h>

#define BB 16
#define CC 256
#define HWP 9216
#define DD 64
#define MM 64

// workspace layout (floats)
#define WS_SCORES 0
#define WS_PROJ   (WS_SCORES + BB * HWP)                       // 147456
#define WS_HG     (WS_PROJ + (size_t)BB * DD * HWP)            // +9437184
#define WS_G      (WS_HG + (size_t)BB * MM * DD)               // +65536
// total = WS_G + BB*MM*CC floats  (~39.7 MB)

// ---------------------------------------------------------------------------
// Kernel A: scores (B,HW) and proj (B,D,HW) from fmap
// grid (144, B), block 256. LDS tile [c][n] (stride 64 -> conflict-free b32)
// ---------------------------------------------------------------------------
__global__ __launch_bounds__(256) void k_score_proj(
    const float* __restrict__ fmap, const float* __restrict__ ws1,
    const float* __restrict__ bs1, const float* __restrict__ ws2,
    const float* __restrict__ bs2, const float* __restrict__ wt2n,
    float* __restrict__ scores, float* __restrict__ proj)
{
    __shared__ float fL[CC * 64];   // 64 KiB, reused for score reduction
    const int b = blockIdx.y;
    const int p0 = blockIdx.x * 64;
    const int t = threadIdx.x;
    const int n = t & 63;
    const int g = t >> 6;           // 0..3

    const float* fb = fmap + (size_t)b * CC * HWP + p0;
    for (int e = t; e < CC * 64; e += 256) {
        const int c = e >> 6, nn = e & 63;
        fL[e] = fb[(size_t)c * HWP + nn];
    }
    __syncthreads();

    float accH[16], accP[16];
#pragma unroll
    for (int j = 0; j < 16; ++j) { accH[j] = bs1[g * 16 + j]; accP[j] = 0.f; }

    for (int c = 0; c < CC; c += 4) {
        const float f0 = fL[(c + 0) * 64 + n];
        const float f1 = fL[(c + 1) * 64 + n];
        const float f2 = fL[(c + 2) * 64 + n];
        const float f3 = fL[(c + 3) * 64 + n];
#pragma unroll
        for (int j = 0; j < 16; ++j) {
            const int o = g * 16 + j;
            const float4 w1 = *(const float4*)&ws1[o * CC + c];
            accH[j] = fmaf(w1.x, f0, fmaf(w1.y, f1, fmaf(w1.z, f2, fmaf(w1.w, f3, accH[j]))));
            const float4 w2 = *(const float4*)&wt2n[o * CC + c];
            accP[j] = fmaf(w2.x, f0, fmaf(w2.y, f1, fmaf(w2.z, f2, fmaf(w2.w, f3, accP[j]))));
        }
    }

    // store proj (coalesced over n)
    float* pb = proj + (size_t)b * DD * HWP + p0;
#pragma unroll
    for (int j = 0; j < 16; ++j) pb[(size_t)(g * 16 + j) * HWP + n] = accP[j];

    // score partial: relu(hid) dot ws2
    float sp = 0.f;
#pragma unroll
    for (int j = 0; j < 16; ++j) sp += ws2[g * 16 + j] * fmaxf(accH[j], 0.f);

    __syncthreads();                 // fL reads done; reuse as reduction buffer
    fL[g * 64 + n] = sp;
    __syncthreads();
    if (t < 64) {
        const float s = fL[t] + fL[64 + t] + fL[128 + t] + fL[192 + t] + bs2[0];
        scores[b * HWP + p0 + t] = s;
    }
}

// ---------------------------------------------------------------------------
// Kernel B: per-batch top-64 + cosine adjacency + 2-layer GCN -> Hg (B,M,D)
// grid (B), block 256
// ---------------------------------------------------------------------------
__global__ __launch_bounds__(256) void k_graph(
    const float* __restrict__ scores, const float* __restrict__ proj,
    const float* __restrict__ wg1, const float* __restrict__ wg2,
    float* __restrict__ HgOut)
{
    __shared__ float sc[HWP];                // scores, later bufA/bufT
    __shared__ float h0x[64 * 65];           // H0, then X
    __shared__ unsigned long long redK[4];
    __shared__ int idxL[64];
    __shared__ float norms[64], rsum[64];

    const int b = blockIdx.x;
    const int t = threadIdx.x;
    const int lane = t & 63, wv = t >> 6;

    for (int i = t; i < HWP; i += 256) sc[i] = scores[b * HWP + i];
    __syncthreads();

    // iterative top-64: packed (ordered-float, HWP-idx) keys, max-reduce
    for (int it = 0; it < 64; ++it) {
        float bv = -3e38f; int bi = 0;
        for (int i = t; i < HWP; i += 256) {
            const float v = sc[i];
            if (v > bv) { bv = v; bi = i; }   // ascending scan: tie keeps lower idx
        }
        unsigned u = __float_as_uint(bv);
        u = (u & 0x80000000u) ? ~u : (u | 0x80000000u);
        unsigned long long key =
            ((unsigned long long)u << 32) | (unsigned)(HWP - bi);
        for (int s = 1; s < 64; s <<= 1) {
            const unsigned long long o = __shfl_xor(key, s, 64);
            if (o > key) key = o;
        }
        if (lane == 0) redK[wv] = key;
        __syncthreads();
        unsigned long long ka = redK[0] > redK[1] ? redK[0] : redK[1];
        const unsigned long long kb2 = redK[2] > redK[3] ? redK[2] : redK[3];
        ka = ka > kb2 ? ka : kb2;
        const int widx = HWP - (int)(ka & 0xFFFFFFFFu);
        if (t == 0) { idxL[it] = widx; sc[widx] = -3e38f; }
        __syncthreads();
    }

    // gather H0[m][d] = proj[b][d][idx[m]]
    for (int e = t; e < 4096; e += 256) {
        const int m = e >> 6, d = e & 63;
        h0x[m * 65 + d] = proj[((size_t)b * DD + d) * HWP + idxL[m]];
    }
    __syncthreads();

    if (t < 64) {
        float s = 0.f;
        for (int d = 0; d < 64; ++d) { const float v = h0x[t * 65 + d]; s = fmaf(v, v, s); }
        norms[t] = fmaxf(sqrtf(s), 1e-6f);
    }
    __syncthreads();

    float* bufA = sc;
    float* bufT = sc + 4160;

    // A = relu(Hn Hn^T) + I
    for (int e = t; e < 4096; e += 256) {
        const int m = e >> 6, nn = e & 63;
        float a = 0.f;
        for (int d = 0; d < 64; ++d) a = fmaf(h0x[m * 65 + d], h0x[nn * 65 + d], a);
        a = fmaxf(a / (norms[m] * norms[nn]), 0.f) + (m == nn ? 1.f : 0.f);
        bufA[m * 65 + nn] = a;
    }
    __syncthreads();
    if (t < 64) {
        float s = 0.f;
        for (int nn = 0; nn < 64; ++nn) s += bufA[t * 65 + nn];
        rsum[t] = fmaxf(s, 1e-6f);
    }
    __syncthreads();
    for (int e = t; e < 4096; e += 256) {
        const int m = e >> 6, nn = e & 63;
        bufA[m * 65 + nn] /= rsum[m];
    }
    __syncthreads();

    // T1 = H0 @ wg1^T
    for (int e = t; e < 4096; e += 256) {
        const int nn = e >> 6, ee = e & 63;
        float a = 0.f;
        for (int d = 0; d < 64; d += 4) {
            const float4 w = *(const float4*)&wg1[ee * 64 + d];
            a = fmaf(w.x, h0x[nn * 65 + d + 0], fmaf(w.y, h0x[nn * 65 + d + 1],
                fmaf(w.z, h0x[nn * 65 + d + 2], fmaf(w.w, h0x[nn * 65 + d + 3], a))));
        }
        bufT[nn * 65 + ee] = a;
    }
    __syncthreads();
    // X = relu(A @ T1) -> h0x
    for (int e = t; e < 4096; e += 256) {
        const int m = e >> 6, ee = e & 63;
        float a = 0.f;
        for (int nn = 0; nn < 64; ++nn) a = fmaf(bufA[m * 65 + nn], bufT[nn * 65 + ee], a);
        h0x[m * 65 + ee] = fmaxf(a, 0.f);
    }
    __syncthreads();
    // T2 = X @ wg2^T -> bufT
    for (int e = t; e < 4096; e += 256) {
        const int nn = e >> 6, ee = e & 63;
        float a = 0.f;
        for (int d = 0; d < 64; d += 4) {
            const float4 w = *(const float4*)&wg2[ee * 64 + d];
            a = fmaf(w.x, h0x[nn * 65 + d + 0], fmaf(w.y, h0x[nn * 65 + d + 1],
                fmaf(w.z, h0x[nn * 65 + d + 2], fmaf(w.w, h0x[nn * 65 + d + 3], a))));
        }
        bufT[nn * 65 + ee] = a;
    }
    __syncthreads();
    // Hg = relu(A @ T2) -> global
    for (int e = t; e < 4096; e += 256) {
        const int m = e >> 6, ee = e & 63;
        float a = 0.f;
        for (int nn = 0; nn < 64; ++nn) a = fmaf(bufA[m * 65 + nn], bufT[nn * 65 + ee], a);
        HgOut[((size_t)b * MM + m) * DD + ee] = fmaxf(a, 0.f);
    }
}

// ---------------------------------------------------------------------------
// Kernel G: G[b][m][c] = sum_d Hg[b][m][d] * wn2t[c][d]   grid (M, B), block 256
// ---------------------------------------------------------------------------
__global__ __launch_bounds__(256) void k_gmat(
    const float* __restrict__ Hg, const float* __restrict__ wn2t,
    float* __restrict__ G)
{
    const int m = blockIdx.x, b = blockIdx.y, c = threadIdx.x;
    __shared__ float hg[64];
    if (c < 64) hg[c] = Hg[((size_t)b * MM + m) * DD + c];
    __syncthreads();
    float a = 0.f;
#pragma unroll
    for (int d = 0; d < 64; d += 4) {
        const float4 w = *(const float4*)&wn2t[c * DD + d];
        a = fmaf(w.x, hg[d + 0], fmaf(w.y, hg[d + 1], fmaf(w.z, hg[d + 2], fmaf(w.w, hg[d + 3], a))));
    }
    G[((size_t)b * MM + m) * CC + c] = a;
}

// ---------------------------------------------------------------------------
// Kernel C: logits -> softmax -> out = fmap + attn @ G
// grid (144, B), block 256
// ---------------------------------------------------------------------------
__global__ __launch_bounds__(256) void k_inject(
    const float* __restrict__ fmap, const float* __restrict__ proj,
    const float* __restrict__ Hg, const float* __restrict__ G,
    float* __restrict__ out)
{
    __shared__ float HgL[64 * 68];    // [m][d], stride 68 (16B-aligned rows)
    __shared__ float attnL[64 * 65];  // [n][m]
    __shared__ float Gc[64 * 68];     // [m][c-local]
    __shared__ float red[4 * 64];

    const int b = blockIdx.y;
    const int p0 = blockIdx.x * 64;
    const int t = threadIdx.x;
    const int n = t & 63, q = t >> 6;

    for (int e = t; e < 4096; e += 256) {
        const int m = e >> 6, d = e & 63;
        HgL[m * 68 + d] = Hg[((size_t)b * MM + m) * DD + d];
    }
    __syncthreads();

    // token row for position p0+n (coalesced over lanes per d)
    float tok[64];
    const float* pb = proj + (size_t)b * DD * HWP + p0 + n;
#pragma unroll
    for (int d = 0; d < 64; ++d) tok[d] = pb[(size_t)d * HWP];

    // logits for 16 m's per thread
    float lg[16];
#pragma unroll
    for (int j = 0; j < 16; ++j) {
        const int m = q * 16 + j;
        float a = 0.f;
#pragma unroll
        for (int d = 0; d < 64; d += 4) {
            const float4 h = *(const float4*)&HgL[m * 68 + d];
            a = fmaf(h.x, tok[d + 0], fmaf(h.y, tok[d + 1],
                fmaf(h.z, tok[d + 2], fmaf(h.w, tok[d + 3], a))));
        }
        lg[j] = a * 0.125f;   // / sqrt(64)
    }

    // softmax over m=64 (partials across the 4 q-groups)
    float lmax = lg[0];
#pragma unroll
    for (int j = 1; j < 16; ++j) lmax = fmaxf(lmax, lg[j]);
    red[q * 64 + n] = lmax;
    __syncthreads();
    const float rmax = fmaxf(fmaxf(red[n], red[64 + n]), fmaxf(red[128 + n], red[192 + n]));
    __syncthreads();
    float lsum = 0.f;
#pragma unroll
    for (int j = 0; j < 16; ++j) { lg[j] = __expf(lg[j] - rmax); lsum += lg[j]; }
    red[q * 64 + n] = lsum;
    __syncthreads();
    const float inv = 1.f / (red[n] + red[64 + n] + red[128 + n] + red[192 + n]);
#pragma unroll
    for (int j = 0; j < 16; ++j) attnL[n * 65 + q * 16 + j] = lg[j] * inv;

    // out tile: 4 positions x 4 channels per thread, G chunked through LDS
    const float* fb = fmap + (size_t)b * CC * HWP + p0;
    float* ob = out + (size_t)b * CC * HWP + p0;
    const int n0 = (t & 15) << 2;
    const int cg = t >> 4;            // 0..15 -> 4-channel group within chunk

    for (int cc = 0; cc < 4; ++cc) {
        __syncthreads();              // attnL ready / Gc reuse safe
        for (int e = t; e < 4096; e += 256) {
            const int m = e >> 6, j = e & 63;
            Gc[m * 68 + j] = G[((size_t)b * MM + m) * CC + cc * 64 + j];
        }
        __syncthreads();

        float acc[4][4];
#pragma unroll
        for (int i = 0; i < 4; ++i)
#pragma unroll
            for (int ci = 0; ci < 4; ++ci) acc[i][ci] = 0.f;

        for (int m = 0; m < 64; ++m) {
            const float4 g4 = *(const float4*)&Gc[m * 68 + cg * 4];
            const float a0 = attnL[(n0 + 0) * 65 + m];
            const float a1 = attnL[(n0 + 1) * 65 + m];
            const float a2 = attnL[(n0 + 2) * 65 + m];
            const float a3 = attnL[(n0 + 3) * 65 + m];
            acc[0][0] = fmaf(a0, g4.x, acc[0][0]); acc[0][1] = fmaf(a0, g4.y, acc[0][1]);
            acc[0][2] = fmaf(a0, g4.z, acc[0][2]); acc[0][3] = fmaf(a0, g4.w, acc[0][3]);
            acc[1][0] = fmaf(a1, g4.x, acc[1][0]); acc[1][1] = fmaf(a1, g4.y, acc[1][1]);
            acc[1][2] = fmaf(a1, g4.z, acc[1][2]); acc[1][3] = fmaf(a1, g4.w, acc[1][3]);
            acc[2][0] = fmaf(a2, g4.x, acc[2][0]); acc[2][1] = fmaf(a2, g4.y, acc[2][1]);
            acc[2][2] = fmaf(a2, g4.z, acc[2][2]); acc[2][3] = fmaf(a2, g4.w, acc[2][3]);
            acc[3][0] = fmaf(a3, g4.x, acc[3][0]); acc[3][1] = fmaf(a3, g4.y, acc[3][1]);
            acc[3][2] = fmaf(a3, g4.z, acc[3][2]); acc[3][3] = fmaf(a3, g4.w, acc[3][3]);
        }

#pragma unroll
        for (int ci = 0; ci < 4; ++ci) {
            const int c = cc * 64 + cg * 4 + ci;
            const float4 f4 = *(const float4*)&fb[(size_t)c * HWP + n0];
            float4 o4;
            o4.x = f4.x + acc[0][ci];
            o4.y = f4.y + acc[1][ci];
            o4.z = f4.z + acc[2][ci];
            o4.w = f4.w + acc[3][ci];
            *(float4*)&ob[(size_t)c * HWP + n0] = o4;
        }
    }
}

// ---------------------------------------------------------------------------
extern "C" void kernel_launch(void* const* d_in, const int* in_sizes, int n_in,
                              void* d_out, int out_size, void* d_ws, size_t ws_size,
                              hipStream_t stream)
{
    const float* fmap = (const float*)d_in[0];
    const float* ws1  = (const float*)d_in[1];
    const float* bs1  = (const float*)d_in[2];
    const float* ws2  = (const float*)d_in[3];
    const float* bs2  = (const float*)d_in[4];
    const float* wt2n = (const float*)d_in[5];
    const float* wn2t = (const float*)d_in[6];
    const float* wg1  = (const float*)d_in[7];
    const float* wg2  = (const float*)d_in[8];
    float* out = (float*)d_out;

    float* wsf    = (float*)d_ws;
    float* scores = wsf + WS_SCORES;
    float* proj   = wsf + WS_PROJ;
    float* HgW    = wsf + WS_HG;
    float* GW     = wsf + WS_G;

    const dim3 blk(256);
    k_score_proj<<<dim3(HWP / 64, BB), blk, 0, stream>>>(fmap, ws1, bs1, ws2, bs2, wt2n, scores, proj);
    k_graph<<<dim3(BB), blk, 0, stream>>>(scores, proj, wg1, wg2, HgW);
    k_gmat<<<dim3(MM, BB), blk, 0, stream>>>(HgW, wn2t, GW);
    k_inject<<<dim3(HWP / 64, BB), blk, 0, stream>>>(fmap, proj, HgW, GW, out);
}

// Round 2
// 314.760 us; speedup vs baseline: 2.6142x; 2.6142x over previous
//
#include <hip/hip_runtime.h>
#include <math.h>

#define BB 16
#define CC 256
#define HWP 9216
#define DD 64
#define MM 64

typedef __attribute__((ext_vector_type(8))) short bf16x8;
typedef __attribute__((ext_vector_type(4))) float f32x4;

__device__ inline unsigned short f2bf(float f) {
    unsigned u = __float_as_uint(f);
    unsigned r = u + 0x7FFFu + ((u >> 16) & 1u);
    return (unsigned short)(r >> 16);
}
__device__ inline float bf2f(unsigned short h) {
    return __uint_as_float(((unsigned)h) << 16);
}

// workspace layout (bytes)
#define WS_SCORES_B 0u                    // fp32 16*9216*4        = 589824
#define WS_PROJ_B   589824u               // bf16 16*64*9216*2     = 18874368
#define WS_HG_B     19464192u             // fp32 16*64*64*4       = 262144
#define WS_G_B      19726336u             // fp32 16*64*256*4      = 1048576
#define WS_WPK_B    20774912u             // bf16 packed W, 65536

// ---------------------------------------------------------------------------
// Prep: pack W = [ws1 (64,256); wt2n (64,256)] into per-lane MFMA A-fragment
// order (stacked-K-halves bijection: slot i<4 -> k=4g+i, i>=4 -> k=16+4g+i-4).
// Layout: wpk[((obg*8 + ks)*64 + lane)*8 + i]. grid 128 x 256.
// ---------------------------------------------------------------------------
__global__ __launch_bounds__(256) void k_prep(
    const float* __restrict__ ws1, const float* __restrict__ wt2n,
    unsigned short* __restrict__ wpk)
{
    const int tid = blockIdx.x * 256 + threadIdx.x;     // 0..32767
    const int i  = tid & 7;
    const int l  = (tid >> 3) & 63;
    const int ks = (tid >> 9) & 7;
    const int ob = tid >> 12;                           // obg 0..7
    const int o = ob * 16 + (l & 15);
    const int g = l >> 4;
    const int k = ks * 32 + (i < 4 ? 4 * g + i : 16 + 4 * g + (i - 4));
    const float v = (o < 64) ? ws1[o * CC + k] : wt2n[(o - 64) * CC + k];
    wpk[tid] = f2bf(v);
}

// ---------------------------------------------------------------------------
// Kernel A (MFMA): per 64-position tile compute D[128][64] = W * F.
// Rows 0-63 = hid -> scores epilogue; rows 64-127 = proj (stored bf16).
// grid (144, B), block 256 (4 waves). Wave w owns o-blocks {2w, 2w+1}.
// LDS: fmap tile as [ck=16][nb=4] subtiles of 16x16 bf16 (tile stride 544B).
// ---------------------------------------------------------------------------
#define TS 272   // tile stride in halfs (544 bytes)

__global__ __launch_bounds__(256) void k_mfma_a(
    const float* __restrict__ fmap, const unsigned short* __restrict__ wpk,
    const float* __restrict__ bs1, const float* __restrict__ ws2,
    const float* __restrict__ bs2,
    float* __restrict__ scores, unsigned short* __restrict__ projW)
{
    __shared__ unsigned short tiles[64 * TS];   // 34816 B
    __shared__ float scoreP[8 * 64];

    const int b = blockIdx.y;
    const int p0 = blockIdx.x * 64;
    const int t = threadIdx.x;
    const int w = t >> 6, l = t & 63;
    const int g = l >> 4, c16 = l & 15;

    // prefetch A fragments: 2 o-blocks x 8 k-steps, 16B/lane coalesced
    const bf16x8* wp = (const bf16x8*)wpk;
    bf16x8 afr[2][8];
#pragma unroll
    for (int ob = 0; ob < 2; ++ob) {
        const int obg = w * 2 + ob;
#pragma unroll
        for (int ks = 0; ks < 8; ++ks) afr[ob][ks] = wp[(obg * 8 + ks) * 64 + l];
    }

    // stage fmap tile -> LDS bf16 subtiles
    const float* fb = fmap + (size_t)b * CC * HWP + p0;
#pragma unroll
    for (int it = 0; it < 16; ++it) {
        const int c = it * 16 + (t >> 4);
        const int n0 = (t & 15) * 4;
        const float4 f4 = *(const float4*)&fb[(size_t)c * HWP + n0];
        const int ck = c >> 4, cr = c & 15, nb = n0 >> 4, nc = n0 & 15;
        ushort4 h4;
        h4.x = f2bf(f4.x); h4.y = f2bf(f4.y); h4.z = f2bf(f4.z); h4.w = f2bf(f4.w);
        *(ushort4*)&tiles[(ck * 4 + nb) * TS + cr * 16 + nc] = h4;
    }
    __syncthreads();

    f32x4 acc[2][4] = {};

#pragma unroll
    for (int ks = 0; ks < 8; ++ks) {
        bf16x8 bfr[4];
#pragma unroll
        for (int nb = 0; nb < 4; ++nb) {
            // tile 2ks (k-half 0) and 2ks+1 (k-half 1); row g*4+j, col c16
            const unsigned short* t0 = &tiles[(8 * ks + nb) * TS + g * 64 + c16];
            const unsigned short* t1 = &tiles[(8 * ks + 4 + nb) * TS + g * 64 + c16];
            bf16x8 f;
#pragma unroll
            for (int j = 0; j < 4; ++j) f[j] = (short)t0[j * 16];
#pragma unroll
            for (int j = 0; j < 4; ++j) f[4 + j] = (short)t1[j * 16];
            bfr[nb] = f;
        }
#pragma unroll
        for (int ob = 0; ob < 2; ++ob)
#pragma unroll
            for (int nb = 0; nb < 4; ++nb)
                acc[ob][nb] = __builtin_amdgcn_mfma_f32_16x16x32_bf16(
                    afr[ob][ks], bfr[nb], acc[ob][nb], 0, 0, 0);
    }

    // epilogue. D element: row o_loc = g*4 + r, col n_loc = c16.
    if (w < 2) {
        float sp[4] = {0.f, 0.f, 0.f, 0.f};
#pragma unroll
        for (int ob = 0; ob < 2; ++ob) {
            const int obase = w * 32 + ob * 16 + g * 4;
#pragma unroll
            for (int r = 0; r < 4; ++r) {
                const int o = obase + r;
                const float b1 = bs1[o], w2 = ws2[o];
#pragma unroll
                for (int nb = 0; nb < 4; ++nb) {
                    const float h = acc[ob][nb][r] + b1;
                    sp[nb] += w2 * fmaxf(h, 0.f);
                }
            }
        }
        const int gw = w * 4 + g;
#pragma unroll
        for (int nb = 0; nb < 4; ++nb) scoreP[gw * 64 + nb * 16 + c16] = sp[nb];
    } else {
        unsigned short* pb = projW + (size_t)b * DD * HWP + p0;
#pragma unroll
        for (int ob = 0; ob < 2; ++ob)
#pragma unroll
            for (int r = 0; r < 4; ++r) {
                const int d = (w - 2) * 32 + ob * 16 + g * 4 + r;
#pragma unroll
                for (int nb = 0; nb < 4; ++nb)
                    pb[(size_t)d * HWP + nb * 16 + c16] = f2bf(acc[ob][nb][r]);
            }
    }
    __syncthreads();
    if (t < 64) {
        float s = bs2[0];
#pragma unroll
        for (int gw = 0; gw < 8; ++gw) s += scoreP[gw * 64 + t];
        scores[b * HWP + p0 + t] = s;
    }
}

// ---------------------------------------------------------------------------
// Kernel B: per-batch top-64 + cosine adjacency + 2-layer GCN -> Hg (B,M,D)
// grid (B), block 256
// ---------------------------------------------------------------------------
__global__ __launch_bounds__(256) void k_graph(
    const float* __restrict__ scores, const unsigned short* __restrict__ projW,
    const float* __restrict__ wg1, const float* __restrict__ wg2,
    float* __restrict__ HgOut)
{
    __shared__ float sc[HWP];
    __shared__ float h0x[64 * 65];
    __shared__ unsigned long long redK[4];
    __shared__ int idxL[64];
    __shared__ float norms[64], rsum[64];

    const int b = blockIdx.x;
    const int t = threadIdx.x;
    const int lane = t & 63, wv = t >> 6;

    for (int i = t; i < HWP; i += 256) sc[i] = scores[b * HWP + i];
    __syncthreads();

    for (int it = 0; it < 64; ++it) {
        float bv = -3e38f; int bi = 0;
        for (int i = t; i < HWP; i += 256) {
            const float v = sc[i];
            if (v > bv) { bv = v; bi = i; }
        }
        unsigned u = __float_as_uint(bv);
        u = (u & 0x80000000u) ? ~u : (u | 0x80000000u);
        unsigned long long key =
            ((unsigned long long)u << 32) | (unsigned)(HWP - bi);
        for (int s = 1; s < 64; s <<= 1) {
            const unsigned long long o = __shfl_xor(key, s, 64);
            if (o > key) key = o;
        }
        if (lane == 0) redK[wv] = key;
        __syncthreads();
        unsigned long long ka = redK[0] > redK[1] ? redK[0] : redK[1];
        const unsigned long long kb2 = redK[2] > redK[3] ? redK[2] : redK[3];
        ka = ka > kb2 ? ka : kb2;
        const int widx = HWP - (int)(ka & 0xFFFFFFFFu);
        if (t == 0) { idxL[it] = widx; sc[widx] = -3e38f; }
        __syncthreads();
    }

    for (int e = t; e < 4096; e += 256) {
        const int m = e >> 6, d = e & 63;
        h0x[m * 65 + d] = bf2f(projW[((size_t)b * DD + d) * HWP + idxL[m]]);
    }
    __syncthreads();

    if (t < 64) {
        float s = 0.f;
        for (int d = 0; d < 64; ++d) { const float v = h0x[t * 65 + d]; s = fmaf(v, v, s); }
        norms[t] = fmaxf(sqrtf(s), 1e-6f);
    }
    __syncthreads();

    float* bufA = sc;
    float* bufT = sc + 4160;

    for (int e = t; e < 4096; e += 256) {
        const int m = e >> 6, nn = e & 63;
        float a = 0.f;
        for (int d = 0; d < 64; ++d) a = fmaf(h0x[m * 65 + d], h0x[nn * 65 + d], a);
        a = fmaxf(a / (norms[m] * norms[nn]), 0.f) + (m == nn ? 1.f : 0.f);
        bufA[m * 65 + nn] = a;
    }
    __syncthreads();
    if (t < 64) {
        float s = 0.f;
        for (int nn = 0; nn < 64; ++nn) s += bufA[t * 65 + nn];
        rsum[t] = fmaxf(s, 1e-6f);
    }
    __syncthreads();
    for (int e = t; e < 4096; e += 256) {
        const int m = e >> 6, nn = e & 63;
        bufA[m * 65 + nn] /= rsum[m];
    }
    __syncthreads();

    for (int e = t; e < 4096; e += 256) {
        const int nn = e >> 6, ee = e & 63;
        float a = 0.f;
        for (int d = 0; d < 64; d += 4) {
            const float4 wv4 = *(const float4*)&wg1[ee * 64 + d];
            a = fmaf(wv4.x, h0x[nn * 65 + d + 0], fmaf(wv4.y, h0x[nn * 65 + d + 1],
                fmaf(wv4.z, h0x[nn * 65 + d + 2], fmaf(wv4.w, h0x[nn * 65 + d + 3], a))));
        }
        bufT[nn * 65 + ee] = a;
    }
    __syncthreads();
    for (int e = t; e < 4096; e += 256) {
        const int m = e >> 6, ee = e & 63;
        float a = 0.f;
        for (int nn = 0; nn < 64; ++nn) a = fmaf(bufA[m * 65 + nn], bufT[nn * 65 + ee], a);
        h0x[m * 65 + ee] = fmaxf(a, 0.f);
    }
    __syncthreads();
    for (int e = t; e < 4096; e += 256) {
        const int nn = e >> 6, ee = e & 63;
        float a = 0.f;
        for (int d = 0; d < 64; d += 4) {
            const float4 wv4 = *(const float4*)&wg2[ee * 64 + d];
            a = fmaf(wv4.x, h0x[nn * 65 + d + 0], fmaf(wv4.y, h0x[nn * 65 + d + 1],
                fmaf(wv4.z, h0x[nn * 65 + d + 2], fmaf(wv4.w, h0x[nn * 65 + d + 3], a))));
        }
        bufT[nn * 65 + ee] = a;
    }
    __syncthreads();
    for (int e = t; e < 4096; e += 256) {
        const int m = e >> 6, ee = e & 63;
        float a = 0.f;
        for (int nn = 0; nn < 64; ++nn) a = fmaf(bufA[m * 65 + nn], bufT[nn * 65 + ee], a);
        HgOut[((size_t)b * MM + m) * DD + ee] = fmaxf(a, 0.f);
    }
}

// ---------------------------------------------------------------------------
// Kernel G: G[b][m][c] = sum_d Hg[b][m][d] * wn2t[c][d]   grid (M, B)
// ---------------------------------------------------------------------------
__global__ __launch_bounds__(256) void k_gmat(
    const float* __restrict__ Hg, const float* __restrict__ wn2t,
    float* __restrict__ G)
{
    const int m = blockIdx.x, b = blockIdx.y, c = threadIdx.x;
    __shared__ float hg[64];
    if (c < 64) hg[c] = Hg[((size_t)b * MM + m) * DD + c];
    __syncthreads();
    float a = 0.f;
#pragma unroll
    for (int d = 0; d < 64; d += 4) {
        const float4 wv4 = *(const float4*)&wn2t[c * DD + d];
        a = fmaf(wv4.x, hg[d + 0], fmaf(wv4.y, hg[d + 1], fmaf(wv4.z, hg[d + 2], fmaf(wv4.w, hg[d + 3], a))));
    }
    G[((size_t)b * MM + m) * CC + c] = a;
}

// ---------------------------------------------------------------------------
// Kernel C: logits -> softmax -> out = fmap + attn @ G.  grid (144, B)
// ---------------------------------------------------------------------------
__global__ __launch_bounds__(256) void k_inject(
    const float* __restrict__ fmap, const unsigned short* __restrict__ projW,
    const float* __restrict__ Hg, const float* __restrict__ G,
    float* __restrict__ out)
{
    __shared__ float HgL[64 * 68];
    __shared__ float attnL[64 * 65];
    __shared__ float Gc[64 * 68];
    __shared__ float red[4 * 64];

    const int b = blockIdx.y;
    const int p0 = blockIdx.x * 64;
    const int t = threadIdx.x;
    const int n = t & 63, q = t >> 6;

    for (int e = t; e < 4096; e += 256) {
        const int m = e >> 6, d = e & 63;
        HgL[m * 68 + d] = Hg[((size_t)b * MM + m) * DD + d];
    }
    __syncthreads();

    float tok[64];
    const unsigned short* pb = projW + (size_t)b * DD * HWP + p0 + n;
#pragma unroll
    for (int d = 0; d < 64; ++d) tok[d] = bf2f(pb[(size_t)d * HWP]);

    float lg[16];
#pragma unroll
    for (int j = 0; j < 16; ++j) {
        const int m = q * 16 + j;
        float a = 0.f;
#pragma unroll
        for (int d = 0; d < 64; d += 4) {
            const float4 h = *(const float4*)&HgL[m * 68 + d];
            a = fmaf(h.x, tok[d + 0], fmaf(h.y, tok[d + 1],
                fmaf(h.z, tok[d + 2], fmaf(h.w, tok[d + 3], a))));
        }
        lg[j] = a * 0.125f;
    }

    float lmax = lg[0];
#pragma unroll
    for (int j = 1; j < 16; ++j) lmax = fmaxf(lmax, lg[j]);
    red[q * 64 + n] = lmax;
    __syncthreads();
    const float rmax = fmaxf(fmaxf(red[n], red[64 + n]), fmaxf(red[128 + n], red[192 + n]));
    __syncthreads();
    float lsum = 0.f;
#pragma unroll
    for (int j = 0; j < 16; ++j) { lg[j] = __expf(lg[j] - rmax); lsum += lg[j]; }
    red[q * 64 + n] = lsum;
    __syncthreads();
    const float inv = 1.f / (red[n] + red[64 + n] + red[128 + n] + red[192 + n]);
#pragma unroll
    for (int j = 0; j < 16; ++j) attnL[n * 65 + q * 16 + j] = lg[j] * inv;

    const float* fb = fmap + (size_t)b * CC * HWP + p0;
    float* ob = out + (size_t)b * CC * HWP + p0;
    const int n0 = (t & 15) << 2;
    const int cg = t >> 4;

    for (int cc = 0; cc < 4; ++cc) {
        __syncthreads();
        for (int e = t; e < 4096; e += 256) {
            const int m = e >> 6, j = e & 63;
            Gc[m * 68 + j] = G[((size_t)b * MM + m) * CC + cc * 64 + j];
        }
        __syncthreads();

        float acc[4][4];
#pragma unroll
        for (int i = 0; i < 4; ++i)
#pragma unroll
            for (int ci = 0; ci < 4; ++ci) acc[i][ci] = 0.f;

        for (int m = 0; m < 64; ++m) {
            const float4 g4 = *(const float4*)&Gc[m * 68 + cg * 4];
            const float a0 = attnL[(n0 + 0) * 65 + m];
            const float a1 = attnL[(n0 + 1) * 65 + m];
            const float a2 = attnL[(n0 + 2) * 65 + m];
            const float a3 = attnL[(n0 + 3) * 65 + m];
            acc[0][0] = fmaf(a0, g4.x, acc[0][0]); acc[0][1] = fmaf(a0, g4.y, acc[0][1]);
            acc[0][2] = fmaf(a0, g4.z, acc[0][2]); acc[0][3] = fmaf(a0, g4.w, acc[0][3]);
            acc[1][0] = fmaf(a1, g4.x, acc[1][0]); acc[1][1] = fmaf(a1, g4.y, acc[1][1]);
            acc[1][2] = fmaf(a1, g4.z, acc[1][2]); acc[1][3] = fmaf(a1, g4.w, acc[1][3]);
            acc[2][0] = fmaf(a2, g4.x, acc[2][0]); acc[2][1] = fmaf(a2, g4.y, acc[2][1]);
            acc[2][2] = fmaf(a2, g4.z, acc[2][2]); acc[2][3] = fmaf(a2, g4.w, acc[2][3]);
            acc[3][0] = fmaf(a3, g4.x, acc[3][0]); acc[3][1] = fmaf(a3, g4.y, acc[3][1]);
            acc[3][2] = fmaf(a3, g4.z, acc[3][2]); acc[3][3] = fmaf(a3, g4.w, acc[3][3]);
        }

#pragma unroll
        for (int ci = 0; ci < 4; ++ci) {
            const int c = cc * 64 + cg * 4 + ci;
            const float4 f4 = *(const float4*)&fb[(size_t)c * HWP + n0];
            float4 o4;
            o4.x = f4.x + acc[0][ci];
            o4.y = f4.y + acc[1][ci];
            o4.z = f4.z + acc[2][ci];
            o4.w = f4.w + acc[3][ci];
            *(float4*)&ob[(size_t)c * HWP + n0] = o4;
        }
    }
}

// ---------------------------------------------------------------------------
extern "C" void kernel_launch(void* const* d_in, const int* in_sizes, int n_in,
                              void* d_out, int out_size, void* d_ws, size_t ws_size,
                              hipStream_t stream)
{
    const float* fmap = (const float*)d_in[0];
    const float* ws1  = (const float*)d_in[1];
    const float* bs1  = (const float*)d_in[2];
    const float* ws2  = (const float*)d_in[3];
    const float* bs2  = (const float*)d_in[4];
    const float* wt2n = (const float*)d_in[5];
    const float* wn2t = (const float*)d_in[6];
    const float* wg1  = (const float*)d_in[7];
    const float* wg2  = (const float*)d_in[8];
    float* out = (float*)d_out;

    char* ws = (char*)d_ws;
    float*          scores = (float*)(ws + WS_SCORES_B);
    unsigned short* projW  = (unsigned short*)(ws + WS_PROJ_B);
    float*          HgW    = (float*)(ws + WS_HG_B);
    float*          GW     = (float*)(ws + WS_G_B);
    unsigned short* wpk    = (unsigned short*)(ws + WS_WPK_B);

    const dim3 blk(256);
    k_prep<<<dim3(128), blk, 0, stream>>>(ws1, wt2n, wpk);
    k_mfma_a<<<dim3(HWP / 64, BB), blk, 0, stream>>>(fmap, wpk, bs1, ws2, bs2, scores, projW);
    k_graph<<<dim3(BB), blk, 0, stream>>>(scores, projW, wg1, wg2, HgW);
    k_gmat<<<dim3(MM, BB), blk, 0, stream>>>(HgW, wn2t, GW);
    k_inject<<<dim3(HWP / 64, BB), blk, 0, stream>>>(fmap, projW, HgW, GW, out);
}

// Round 3
// 186.962 us; speedup vs baseline: 4.4012x; 1.6836x over previous
//
#include <hip/hip_runtime.h>
#include <math.h>

#define BB 16
#define CC 256
#define HWP 9216
#define DD 64
#define MM 64

typedef __attribute__((ext_vector_type(8))) short bf16x8;
typedef __attribute__((ext_vector_type(4))) float f32x4;

__device__ inline unsigned short f2bf(float f) {
    unsigned u = __float_as_uint(f);
    unsigned r = u + 0x7FFFu + ((u >> 16) & 1u);
    return (unsigned short)(r >> 16);
}
__device__ inline float bf2f(unsigned short h) {
    return __uint_as_float(((unsigned)h) << 16);
}

// workspace layout (bytes)
#define WS_SCORES_B 0u                    // fp32 16*9216*4        = 589824
#define WS_PROJ_B   589824u               // bf16 16*64*9216*2     = 18874368
#define WS_HG_B     19464192u             // fp32 16*64*64*4       = 262144
#define WS_HGPK_B   19726336u             // bf16 16*4096*2        = 131072
#define WS_GPK_B    19857408u             // bf16 16*16384*2       = 524288
#define WS_WPK_B    20381696u             // bf16 packed W, 65536

// k index bijection used by ALL fragments (verified on HW in round 2):
// kmap(g, j) = j<4 ? g*4+j : 16+g*4+(j-4)

// ---------------------------------------------------------------------------
// Prep: pack W = [ws1 (64,256); wt2n (64,256)] into per-lane MFMA A-fragment
// order. Layout: wpk[((obg*8 + ks)*64 + lane)*8 + j]. grid 128 x 256.
// ---------------------------------------------------------------------------
__global__ __launch_bounds__(256) void k_prep(
    const float* __restrict__ ws1, const float* __restrict__ wt2n,
    unsigned short* __restrict__ wpk)
{
    const int tid = blockIdx.x * 256 + threadIdx.x;     // 0..32767
    const int i  = tid & 7;
    const int l  = (tid >> 3) & 63;
    const int ks = (tid >> 9) & 7;
    const int ob = tid >> 12;                           // obg 0..7
    const int o = ob * 16 + (l & 15);
    const int g = l >> 4;
    const int k = ks * 32 + (i < 4 ? 4 * g + i : 16 + 4 * g + (i - 4));
    const float v = (o < 64) ? ws1[o * CC + k] : wt2n[(o - 64) * CC + k];
    wpk[tid] = f2bf(v);
}

// ---------------------------------------------------------------------------
// Kernel A (MFMA): per 64-position tile compute D[128][64] = W * F.
// Rows 0-63 = hid -> scores epilogue; rows 64-127 = proj (stored bf16).
// grid (144, B), block 256 (4 waves).
// ---------------------------------------------------------------------------
#define TS 272   // tile stride in halfs (544 bytes)

__global__ __launch_bounds__(256) void k_mfma_a(
    const float* __restrict__ fmap, const unsigned short* __restrict__ wpk,
    const float* __restrict__ bs1, const float* __restrict__ ws2,
    const float* __restrict__ bs2,
    float* __restrict__ scores, unsigned short* __restrict__ projW)
{
    __shared__ unsigned short tiles[64 * TS];   // 34816 B
    __shared__ float scoreP[8 * 64];

    const int b = blockIdx.y;
    const int p0 = blockIdx.x * 64;
    const int t = threadIdx.x;
    const int w = t >> 6, l = t & 63;
    const int g = l >> 4, c16 = l & 15;

    const bf16x8* wp = (const bf16x8*)wpk;
    bf16x8 afr[2][8];
#pragma unroll
    for (int ob = 0; ob < 2; ++ob) {
        const int obg = w * 2 + ob;
#pragma unroll
        for (int ks = 0; ks < 8; ++ks) afr[ob][ks] = wp[(obg * 8 + ks) * 64 + l];
    }

    const float* fb = fmap + (size_t)b * CC * HWP + p0;
#pragma unroll
    for (int it = 0; it < 16; ++it) {
        const int c = it * 16 + (t >> 4);
        const int n0 = (t & 15) * 4;
        const float4 f4 = *(const float4*)&fb[(size_t)c * HWP + n0];
        const int ck = c >> 4, cr = c & 15, nb = n0 >> 4, nc = n0 & 15;
        ushort4 h4;
        h4.x = f2bf(f4.x); h4.y = f2bf(f4.y); h4.z = f2bf(f4.z); h4.w = f2bf(f4.w);
        *(ushort4*)&tiles[(ck * 4 + nb) * TS + cr * 16 + nc] = h4;
    }
    __syncthreads();

    f32x4 acc[2][4] = {};

#pragma unroll
    for (int ks = 0; ks < 8; ++ks) {
        bf16x8 bfr[4];
#pragma unroll
        for (int nb = 0; nb < 4; ++nb) {
            const unsigned short* t0 = &tiles[(8 * ks + nb) * TS + g * 64 + c16];
            const unsigned short* t1 = &tiles[(8 * ks + 4 + nb) * TS + g * 64 + c16];
            bf16x8 f;
#pragma unroll
            for (int j = 0; j < 4; ++j) f[j] = (short)t0[j * 16];
#pragma unroll
            for (int j = 0; j < 4; ++j) f[4 + j] = (short)t1[j * 16];
            bfr[nb] = f;
        }
#pragma unroll
        for (int ob = 0; ob < 2; ++ob)
#pragma unroll
            for (int nb = 0; nb < 4; ++nb)
                acc[ob][nb] = __builtin_amdgcn_mfma_f32_16x16x32_bf16(
                    afr[ob][ks], bfr[nb], acc[ob][nb], 0, 0, 0);
    }

    if (w < 2) {
        float sp[4] = {0.f, 0.f, 0.f, 0.f};
#pragma unroll
        for (int ob = 0; ob < 2; ++ob) {
            const int obase = w * 32 + ob * 16 + g * 4;
#pragma unroll
            for (int r = 0; r < 4; ++r) {
                const int o = obase + r;
                const float b1 = bs1[o], w2 = ws2[o];
#pragma unroll
                for (int nb = 0; nb < 4; ++nb) {
                    const float h = acc[ob][nb][r] + b1;
                    sp[nb] += w2 * fmaxf(h, 0.f);
                }
            }
        }
        const int gw = w * 4 + g;
#pragma unroll
        for (int nb = 0; nb < 4; ++nb) scoreP[gw * 64 + nb * 16 + c16] = sp[nb];
    } else {
        unsigned short* pb = projW + (size_t)b * DD * HWP + p0;
#pragma unroll
        for (int ob = 0; ob < 2; ++ob)
#pragma unroll
            for (int r = 0; r < 4; ++r) {
                const int d = (w - 2) * 32 + ob * 16 + g * 4 + r;
#pragma unroll
                for (int nb = 0; nb < 4; ++nb)
                    pb[(size_t)d * HWP + nb * 16 + c16] = f2bf(acc[ob][nb][r]);
            }
    }
    __syncthreads();
    if (t < 64) {
        float s = bs2[0];
#pragma unroll
        for (int gw = 0; gw < 8; ++gw) s += scoreP[gw * 64 + t];
        scores[b * HWP + p0 + t] = s;
    }
}

// ---------------------------------------------------------------------------
// Kernel B: radix-select top-64 + cosine adjacency + 2-layer GCN.
// Outputs Hg fp32 (for k_gmat) and HgPk bf16 fragment-packed (for k_inject).
// grid (B), block 256
// ---------------------------------------------------------------------------
__global__ __launch_bounds__(256) void k_graph(
    const float* __restrict__ scores, const unsigned short* __restrict__ projW,
    const float* __restrict__ wg1, const float* __restrict__ wg2,
    float* __restrict__ HgOut, unsigned short* __restrict__ HgPk)
{
    __shared__ float h0x[64 * 65];
    __shared__ float bufA[64 * 65];
    __shared__ float bufT[64 * 65];
    __shared__ int hist[256];
    __shared__ int idxL[64];
    __shared__ int eqIdx[64];
    __shared__ int sInts[8];          // [0]=digit [1]=cntGt [2]=selCnt [3]=eqCnt
    __shared__ float norms[64], rsum[64];

    const int b = blockIdx.x;
    const int t = threadIdx.x;

    // scores -> ordered-uint keys in registers (strided, coalesced)
    unsigned uv[36];
#pragma unroll
    for (int i = 0; i < 36; ++i) {
        const unsigned u = __float_as_uint(scores[b * HWP + i * 256 + t]);
        uv[i] = (u >> 31) ? ~u : (u | 0x80000000u);
    }

    // MSB-first radix select: find exact pivot P with cnt(u>P) < 64 <= cnt(u>=P)
    unsigned prefix = 0;
    int need = 64;
    for (int pass = 0; pass < 4; ++pass) {
        const int shift = 24 - 8 * pass;
        hist[t] = 0;
        __syncthreads();
#pragma unroll
        for (int i = 0; i < 36; ++i) {
            const bool ok = (pass == 0) || ((uv[i] >> (shift + 8)) == prefix);
            if (ok) atomicAdd(&hist[(uv[i] >> shift) & 255], 1);
        }
        __syncthreads();
        if (t < 64) {
            const int l = t;
            const int h0 = hist[4 * l + 0], h1 = hist[4 * l + 1];
            const int h2 = hist[4 * l + 2], h3 = hist[4 * l + 3];
            const int T = h0 + h1 + h2 + h3;
            int S = T;                      // inclusive suffix over lanes
            for (int st = 1; st < 64; st <<= 1) {
                const int v = __shfl_down(S, st, 64);
                if (l + st < 64) S += v;
            }
            const int Sexc = S - T;
            const int ge3 = Sexc + h3, ge2 = ge3 + h2, ge1 = ge2 + h1, ge0 = ge1 + h0;
            if (ge3 - h3 < need && need <= ge3) { sInts[0] = 4 * l + 3; sInts[1] = ge3 - h3; }
            if (ge2 - h2 < need && need <= ge2) { sInts[0] = 4 * l + 2; sInts[1] = ge2 - h2; }
            if (ge1 - h1 < need && need <= ge1) { sInts[0] = 4 * l + 1; sInts[1] = ge1 - h1; }
            if (ge0 - h0 < need && need <= ge0) { sInts[0] = 4 * l + 0; sInts[1] = ge0 - h0; }
        }
        __syncthreads();
        prefix = (prefix << 8) | (unsigned)sInts[0];
        need -= sInts[1];
        __syncthreads();
    }

    if (t == 0) { sInts[2] = 0; sInts[3] = 0; }
    __syncthreads();
    const unsigned P = prefix;
    const int needEq = need;              // how many u==P to take (lowest idx)
#pragma unroll
    for (int i = 0; i < 36; ++i) {
        const unsigned u = uv[i];
        const int idx = i * 256 + t;
        if (u > P) { const int p = atomicAdd(&sInts[2], 1); idxL[p] = idx; }
        else if (u == P) { const int p = atomicAdd(&sInts[3], 1); if (p < 64) eqIdx[p] = idx; }
    }
    __syncthreads();
    if (t == 0) {
        int ec = sInts[3]; if (ec > 64) ec = 64;
        const int base = sInts[2];
        for (int k2 = 0; k2 < needEq; ++k2) {
            int mn = 0x7FFFFFFF, mi = 0;
            for (int j = 0; j < ec; ++j) if (eqIdx[j] < mn) { mn = eqIdx[j]; mi = j; }
            idxL[base + k2] = mn; eqIdx[mi] = 0x7FFFFFFF;
        }
    }
    __syncthreads();

    // gather H0[m][d] = proj[b][d][idx[m]]
    for (int e = t; e < 4096; e += 256) {
        const int m = e >> 6, d = e & 63;
        h0x[m * 65 + d] = bf2f(projW[((size_t)b * DD + d) * HWP + idxL[m]]);
    }
    __syncthreads();

    if (t < 64) {
        float s = 0.f;
        for (int d = 0; d < 64; ++d) { const float v = h0x[t * 65 + d]; s = fmaf(v, v, s); }
        norms[t] = fmaxf(sqrtf(s), 1e-6f);
    }
    __syncthreads();

    // A = relu(Hn Hn^T) + I, row-normalized
    for (int e = t; e < 4096; e += 256) {
        const int m = e >> 6, nn = e & 63;
        float a = 0.f;
        for (int d = 0; d < 64; ++d) a = fmaf(h0x[m * 65 + d], h0x[nn * 65 + d], a);
        a = fmaxf(a / (norms[m] * norms[nn]), 0.f) + (m == nn ? 1.f : 0.f);
        bufA[m * 65 + nn] = a;
    }
    __syncthreads();
    if (t < 64) {
        float s = 0.f;
        for (int nn = 0; nn < 64; ++nn) s += bufA[t * 65 + nn];
        rsum[t] = fmaxf(s, 1e-6f);
    }
    __syncthreads();
    for (int e = t; e < 4096; e += 256) {
        const int m = e >> 6, nn = e & 63;
        bufA[m * 65 + nn] /= rsum[m];
    }
    __syncthreads();

    // T1 = H0 @ wg1^T
    for (int e = t; e < 4096; e += 256) {
        const int nn = e >> 6, ee = e & 63;
        float a = 0.f;
        for (int d = 0; d < 64; d += 4) {
            const float4 wv4 = *(const float4*)&wg1[ee * 64 + d];
            a = fmaf(wv4.x, h0x[nn * 65 + d + 0], fmaf(wv4.y, h0x[nn * 65 + d + 1],
                fmaf(wv4.z, h0x[nn * 65 + d + 2], fmaf(wv4.w, h0x[nn * 65 + d + 3], a))));
        }
        bufT[nn * 65 + ee] = a;
    }
    __syncthreads();
    // X = relu(A @ T1) -> h0x
    for (int e = t; e < 4096; e += 256) {
        const int m = e >> 6, ee = e & 63;
        float a = 0.f;
        for (int nn = 0; nn < 64; ++nn) a = fmaf(bufA[m * 65 + nn], bufT[nn * 65 + ee], a);
        h0x[m * 65 + ee] = fmaxf(a, 0.f);
    }
    __syncthreads();
    // T2 = X @ wg2^T
    for (int e = t; e < 4096; e += 256) {
        const int nn = e >> 6, ee = e & 63;
        float a = 0.f;
        for (int d = 0; d < 64; d += 4) {
            const float4 wv4 = *(const float4*)&wg2[ee * 64 + d];
            a = fmaf(wv4.x, h0x[nn * 65 + d + 0], fmaf(wv4.y, h0x[nn * 65 + d + 1],
                fmaf(wv4.z, h0x[nn * 65 + d + 2], fmaf(wv4.w, h0x[nn * 65 + d + 3], a))));
        }
        bufT[nn * 65 + ee] = a;
    }
    __syncthreads();
    // Hg = relu(A @ T2) -> h0x + global fp32
    for (int e = t; e < 4096; e += 256) {
        const int m = e >> 6, ee = e & 63;
        float a = 0.f;
        for (int nn = 0; nn < 64; ++nn) a = fmaf(bufA[m * 65 + nn], bufT[nn * 65 + ee], a);
        a = fmaxf(a, 0.f);
        h0x[m * 65 + ee] = a;
        HgOut[((size_t)b * MM + m) * DD + ee] = a;
    }
    __syncthreads();
    // HgPk: fragment-packed bf16 (B-operand: cols m, k = d)
    for (int e = t; e < 4096; e += 256) {
        const int j = e & 7, l = (e >> 3) & 63, ks = (e >> 9) & 1, mb = e >> 10;
        const int m = mb * 16 + (l & 15);
        const int g = l >> 4;
        const int km = (j < 4) ? g * 4 + j : 16 + g * 4 + (j - 4);
        HgPk[(size_t)b * 4096 + e] = f2bf(h0x[m * 65 + ks * 32 + km]);
    }
}

// ---------------------------------------------------------------------------
// Kernel G: Gpk fragment-packed bf16 of G[m][c] = sum_d Hg[m][d] wn2t[c][d].
// A-operand layout for phase 3: rows c, k = m. grid (M, B), block 256.
// ---------------------------------------------------------------------------
__global__ __launch_bounds__(256) void k_gmat(
    const float* __restrict__ Hg, const float* __restrict__ wn2t,
    unsigned short* __restrict__ Gpk)
{
    const int m = blockIdx.x, b = blockIdx.y, c = threadIdx.x;
    __shared__ float hg[64];
    if (c < 64) hg[c] = Hg[((size_t)b * MM + m) * DD + c];
    __syncthreads();
    float a = 0.f;
#pragma unroll
    for (int d = 0; d < 64; d += 4) {
        const float4 wv4 = *(const float4*)&wn2t[c * DD + d];
        a = fmaf(wv4.x, hg[d + 0], fmaf(wv4.y, hg[d + 1], fmaf(wv4.z, hg[d + 2], fmaf(wv4.w, hg[d + 3], a))));
    }
    // pack: (c, m) -> [((cb*2+ks)*64 + g*16 + c16)*8 + j]
    const int cb = c >> 4, c16 = c & 15;
    const int ks = m >> 5, km = m & 31;
    const int g = (km < 16) ? (km >> 2) : ((km - 16) >> 2);
    const int j = (km < 16) ? (km & 3) : 4 + ((km - 16) & 3);
    Gpk[(size_t)b * 16384 + ((cb * 2 + ks) * 64 + g * 16 + c16) * 8 + j] = f2bf(a);
}

// ---------------------------------------------------------------------------
// Kernel C (MFMA): logits -> softmax -> out = fmap + attn @ G.
// grid (144, B), block 256 (4 waves, wave = n-block nb).
// Phase 1: L[n][m] = tok·Hg^T /8  (A = tok rows n, B = HgPk cols m)
// Phase 3: D[c][n] = G^T·attn^T   (A = Gpk rows c,  B = attn cols n)
// ---------------------------------------------------------------------------
__global__ __launch_bounds__(256) void k_inject(
    const float* __restrict__ fmap, const unsigned short* __restrict__ projW,
    const unsigned short* __restrict__ HgPk, const unsigned short* __restrict__ Gpk,
    float* __restrict__ out)
{
    __shared__ unsigned short pjL[64 * 72];    // proj tile [d][n], pad 72
    __shared__ unsigned short attnL[64 * 72];  // attn [n][m], pad 72

    const int b = blockIdx.y;
    const int p0 = blockIdx.x * 64;
    const int t = threadIdx.x;
    const int nb = t >> 6, l = t & 63;
    const int g = l >> 4, c16 = l & 15;

    // stage proj tile (coalesced ushort4)
    {
        const unsigned short* pbase = projW + (size_t)b * DD * HWP + p0;
#pragma unroll
        for (int k2 = 0; k2 < 4; ++k2) {
            const int idx = k2 * 256 + t;          // 0..1023
            const int d = idx >> 4, c4 = idx & 15;
            const ushort4 v = *(const ushort4*)&pbase[(size_t)d * HWP + c4 * 4];
            *(ushort4*)&pjL[d * 72 + c4 * 4] = v;
        }
    }

    // B-frags for logits from HgPk (global, L2) — independent of LDS
    bf16x8 bhg[4][2];
    {
        const bf16x8* hp = (const bf16x8*)(HgPk + (size_t)b * 4096);
#pragma unroll
        for (int mb = 0; mb < 4; ++mb)
#pragma unroll
            for (int ks = 0; ks < 2; ++ks) bhg[mb][ks] = hp[(mb * 2 + ks) * 64 + l];
    }
    __syncthreads();

    // A-frags: tok rows n = nb*16 + c16
    bf16x8 atok[2];
#pragma unroll
    for (int ks = 0; ks < 2; ++ks) {
        bf16x8 f;
#pragma unroll
        for (int j = 0; j < 8; ++j) {
            const int km = (j < 4) ? g * 4 + j : 16 + g * 4 + (j - 4);
            f[j] = (short)pjL[(ks * 32 + km) * 72 + nb * 16 + c16];
        }
        atok[ks] = f;
    }

    f32x4 accL[4] = {};
#pragma unroll
    for (int ks = 0; ks < 2; ++ks)
#pragma unroll
        for (int mb = 0; mb < 4; ++mb)
            accL[mb] = __builtin_amdgcn_mfma_f32_16x16x32_bf16(atok[ks], bhg[mb][ks], accL[mb], 0, 0, 0);

    // lane holds L[n = nb*16 + g*4 + r][m = mb*16 + c16] — softmax over m
#pragma unroll
    for (int mb = 0; mb < 4; ++mb)
#pragma unroll
        for (int r = 0; r < 4; ++r) accL[mb][r] *= 0.125f;

    float mx[4], sm[4], inv[4];
#pragma unroll
    for (int r = 0; r < 4; ++r)
        mx[r] = fmaxf(fmaxf(accL[0][r], accL[1][r]), fmaxf(accL[2][r], accL[3][r]));
#pragma unroll
    for (int st = 1; st < 16; st <<= 1)
#pragma unroll
        for (int r = 0; r < 4; ++r) mx[r] = fmaxf(mx[r], __shfl_xor(mx[r], st, 64));
#pragma unroll
    for (int r = 0; r < 4; ++r) sm[r] = 0.f;
#pragma unroll
    for (int mb = 0; mb < 4; ++mb)
#pragma unroll
        for (int r = 0; r < 4; ++r) {
            const float e = __expf(accL[mb][r] - mx[r]);
            accL[mb][r] = e; sm[r] += e;
        }
#pragma unroll
    for (int st = 1; st < 16; st <<= 1)
#pragma unroll
        for (int r = 0; r < 4; ++r) sm[r] += __shfl_xor(sm[r], st, 64);
#pragma unroll
    for (int r = 0; r < 4; ++r) inv[r] = 1.f / sm[r];

#pragma unroll
    for (int mb = 0; mb < 4; ++mb)
#pragma unroll
        for (int r = 0; r < 4; ++r)
            attnL[(nb * 16 + g * 4 + r) * 72 + mb * 16 + c16] = f2bf(accL[mb][r] * inv[r]);
    __syncthreads();

    // B-frags: attn cols n = nb*16 + c16 (each wave its own rows)
    const int nrow = nb * 16 + c16;
    bf16x8 battn[2];
#pragma unroll
    for (int ks = 0; ks < 2; ++ks) {
        const ushort4 lo = *(const ushort4*)&attnL[nrow * 72 + ks * 32 + g * 4];
        const ushort4 hi = *(const ushort4*)&attnL[nrow * 72 + ks * 32 + 16 + g * 4];
        bf16x8 f;
        f[0] = (short)lo.x; f[1] = (short)lo.y; f[2] = (short)lo.z; f[3] = (short)lo.w;
        f[4] = (short)hi.x; f[5] = (short)hi.y; f[6] = (short)hi.z; f[7] = (short)hi.w;
        battn[ks] = f;
    }

    const bf16x8* gp = (const bf16x8*)(Gpk + (size_t)b * 16384);
    const float* fb = fmap + (size_t)b * CC * HWP + p0 + nb * 16 + c16;
    float* ob = out + (size_t)b * CC * HWP + p0 + nb * 16 + c16;

#pragma unroll
    for (int cb = 0; cb < 16; ++cb) {
        f32x4 acc = {};
#pragma unroll
        for (int ks = 0; ks < 2; ++ks)
            acc = __builtin_amdgcn_mfma_f32_16x16x32_bf16(gp[(cb * 2 + ks) * 64 + l], battn[ks], acc, 0, 0, 0);
#pragma unroll
        for (int r = 0; r < 4; ++r) {
            const size_t off = (size_t)(cb * 16 + g * 4 + r) * HWP;
            ob[off] = fb[off] + acc[r];
        }
    }
}

// ---------------------------------------------------------------------------
extern "C" void kernel_launch(void* const* d_in, const int* in_sizes, int n_in,
                              void* d_out, int out_size, void* d_ws, size_t ws_size,
                              hipStream_t stream)
{
    const float* fmap = (const float*)d_in[0];
    const float* ws1  = (const float*)d_in[1];
    const float* bs1  = (const float*)d_in[2];
    const float* ws2  = (const float*)d_in[3];
    const float* bs2  = (const float*)d_in[4];
    const float* wt2n = (const float*)d_in[5];
    const float* wn2t = (const float*)d_in[6];
    const float* wg1  = (const float*)d_in[7];
    const float* wg2  = (const float*)d_in[8];
    float* out = (float*)d_out;

    char* ws = (char*)d_ws;
    float*          scores = (float*)(ws + WS_SCORES_B);
    unsigned short* projW  = (unsigned short*)(ws + WS_PROJ_B);
    float*          HgW    = (float*)(ws + WS_HG_B);
    unsigned short* HgPk   = (unsigned short*)(ws + WS_HGPK_B);
    unsigned short* Gpk    = (unsigned short*)(ws + WS_GPK_B);
    unsigned short* wpk    = (unsigned short*)(ws + WS_WPK_B);

    const dim3 blk(256);
    k_prep<<<dim3(128), blk, 0, stream>>>(ws1, wt2n, wpk);
    k_mfma_a<<<dim3(HWP / 64, BB), blk, 0, stream>>>(fmap, wpk, bs1, ws2, bs2, scores, projW);
    k_graph<<<dim3(BB), blk, 0, stream>>>(scores, projW, wg1, wg2, HgW, HgPk);
    k_gmat<<<dim3(MM, BB), blk, 0, stream>>>(HgW, wn2t, Gpk);
    k_inject<<<dim3(HWP / 64, BB), blk, 0, stream>>>(fmap, projW, HgPk, Gpk, out);
}